// Round 8
// baseline (178.547 us; speedup 1.0000x reference)
//
#include <hip/hip_runtime.h>

// NonMaxSuppression (Canny thinning), H=W=4096, fp32.
//
// R7: zero-divergence, zero-DS kernel. Per quad the 3x6 neighborhood comes
// from 9 overlapping dwordx4 loads (aligned + unaligned left/right windows;
// the overlap hits neighbors' cache lines -> L1/L2 absorb it). All 10 loads
// issue in one clause -> one vmcnt wait -> straight-line VALU -> NT store.
// Boundary handling: clamp addresses for validity, zero values with
// predicated multiplies (no branches, no exec-mask fragments, no shuffles).
// Pair-max: min(pos,neg)>0 <=> m > M[c&3], M[j]=max(n_j-b_j, n_{j+4}-b_{j+4}).

constexpr int H = 4096;
constexpr int W = 4096;
constexpr long NPX = (long)H * W;

typedef float v4f __attribute__((ext_vector_type(4)));

__device__ __forceinline__ v4f ldv(const float* __restrict__ p, long idx) {
    return *reinterpret_cast<const v4f*>(p + idx);
}

__global__ __launch_bounds__(256) void nms_kernel(
    const float* __restrict__ mag,
    const float* __restrict__ orient,
    const float* __restrict__ bias,
    float* __restrict__ out)
{
    const int tid = blockIdx.x * 256 + threadIdx.x;   // [0, H*W/4)
    const int y   = tid >> 10;                        // quad row
    const int x0  = (tid & 1023) << 2;
    const long base = ((long)y << 12) + x0;

    // row-clamped bases (address validity only; values masked below)
    const long ubase = (y > 0)     ? base - W : base;
    const long dbase = (y < H - 1) ? base + W : base;

    // ---- one load clause: 9 mag + 1 orient, all independent ----
    const v4f cA = ldv(mag, base);
    const v4f cL = ldv(mag, (base - 4 > 0) ? base - 4 : 0);
    const v4f cR = ldv(mag, (base + 4 < NPX - 4) ? base + 4 : NPX - 4);
    const v4f uA = ldv(mag, ubase);
    const v4f uL = ldv(mag, (ubase - 4 > 0) ? ubase - 4 : 0);
    const v4f uR = ldv(mag, (ubase + 4 < NPX - 4) ? ubase + 4 : NPX - 4);
    const v4f dA = ldv(mag, dbase);
    const v4f dL = ldv(mag, (dbase - 4 > 0) ? dbase - 4 : 0);
    const v4f dR = ldv(mag, (dbase + 4 < NPX - 4) ? dbase + 4 : NPX - 4);
    const v4f o4 = ldv(orient, base);

    // bias (scalar loads, uniform address)
    float b[8];
    #pragma unroll
    for (int i = 0; i < 8; ++i) b[i] = bias[i];

    // ---- boundary masks (predicated multiplies, no branches) ----
    const float um = (y > 0)      ? 1.f : 0.f;
    const float dm = (y < H - 1)  ? 1.f : 0.f;
    const float lm = (x0 > 0)     ? 1.f : 0.f;
    const float rm = (x0 + 4 < W) ? 1.f : 0.f;

    const float u6[6] = {uL.w * (um * lm), uA.x * um, uA.y * um,
                         uA.z * um, uA.w * um, uR.x * (um * rm)};
    const float c6[6] = {cL.w * lm, cA.x, cA.y, cA.z, cA.w, cR.x * rm};
    const float d6[6] = {dL.w * (dm * lm), dA.x * dm, dA.y * dm,
                         dA.z * dm, dA.w * dm, dR.x * (dm * rm)};

    const float m[4] = {cA.x, cA.y, cA.z, cA.w};
    const float o[4] = {o4.x, o4.y, o4.z, o4.w};

    // direction (dy,dx) by c:
    // 0:(0,1) 1:(1,1) 2:(1,0) 3:(1,-1) 4:(0,-1) 5:(-1,-1) 6:(-1,0) 7:(-1,1)
    float r[4];
    #pragma unroll
    for (int k = 0; k < 4; ++k) {
        // orient is an exact multiple of 45 in [0,315]; mul+0.5+trunc
        // absorbs the 1-ulp reciprocal error. Only c&3 matters (pair-max).
        const int c = (int)(o[k] * 0.0222222222f + 0.5f);
        const bool b0 = (c & 1), b1 = (c & 2);

        const float M0 = fmaxf(c6[k + 2] - b[0], c6[k]     - b[4]);
        const float M1 = fmaxf(d6[k + 2] - b[1], u6[k]     - b[5]);
        const float M2 = fmaxf(d6[k + 1] - b[2], u6[k + 1] - b[6]);
        const float M3 = fmaxf(d6[k]     - b[3], u6[k + 2] - b[7]);

        const float m01 = b0 ? M1 : M0;
        const float m23 = b0 ? M3 : M2;
        const float Mj  = b1 ? m23 : m01;

        r[k] = (m[k] > Mj) ? m[k] : 0.0f;   // min(pos,neg)>0 <=> m>M[c&3]
    }

    v4f res; res.x = r[0]; res.y = r[1]; res.z = r[2]; res.w = r[3];
    __builtin_nontemporal_store(res, reinterpret_cast<v4f*>(out + base));
}

extern "C" void kernel_launch(void* const* d_in, const int* in_sizes, int n_in,
                              void* d_out, int out_size, void* d_ws, size_t ws_size,
                              hipStream_t stream) {
    const float* mag    = (const float*)d_in[0];   // [1,1,H,W]
    const float* orient = (const float*)d_in[1];   // [1,1,H,W]
    // d_in[2] = weight [8,1,3,3] -- fixed directional filters, hardcoded
    const float* bias   = (const float*)d_in[3];   // [8]
    float* out = (float*)d_out;                    // [1,1,H,W]

    const int total = H * (W / 4);                 // one thread per quad
    dim3 block(256);
    dim3 grid(total / 256);                        // 16384 blocks
    hipLaunchKernelGGL(nms_kernel, grid, block, 0, stream,
                       mag, orient, bias, out);
}

// Round 9
// 177.843 us; speedup vs baseline: 1.0040x; 1.0040x over previous
//
#include <hip/hip_runtime.h>

// NonMaxSuppression (Canny thinning), H=W=4096, fp32.
//
// R8: R4 champion geometry (4 rows x 4 cols per thread, XCD band swizzle for
// vertical L2 locality) with the R7 lesson applied: NO shuffles, NO divergent
// patch sections. Halo columns come from unconditional per-lane dword loads
// (clamped addresses, 0/1-multiply masking). One load clause of 22
// independent loads -> one wait -> straight-line VALU -> 4 NT stores.
// Pair-max: min(pos,neg)>0 <=> m > M[c&3], M[j]=max(n_j-b_j, n_{j+4}-b_{j+4}).

constexpr int H = 4096;
constexpr int W = 4096;

typedef float v4f __attribute__((ext_vector_type(4)));

// NMS for 4 px given 6-wide window rows u6 (y-1), c6 (y), d6 (y+1).
// Direction (dy,dx) by c:
// 0:(0,1) 1:(1,1) 2:(1,0) 3:(1,-1) 4:(0,-1) 5:(-1,-1) 6:(-1,0) 7:(-1,1)
__device__ __forceinline__ v4f nms_quad(const float u6[6], const float c6[6],
                                        const float d6[6], v4f m4, v4f o4,
                                        const float b[8])
{
    const float m[4] = {m4.x, m4.y, m4.z, m4.w};
    const float o[4] = {o4.x, o4.y, o4.z, o4.w};
    float r[4];
    #pragma unroll
    for (int k = 0; k < 4; ++k) {
        // orient is an exact multiple of 45 in [0,315]; mul+0.5+trunc
        // absorbs the 1-ulp reciprocal error. Only c&3 matters (pair-max).
        const int c = (int)(o[k] * 0.0222222222f + 0.5f);
        const bool b0 = (c & 1), b1 = (c & 2);

        const float M0 = fmaxf(c6[k + 2] - b[0], c6[k]     - b[4]);
        const float M1 = fmaxf(d6[k + 2] - b[1], u6[k]     - b[5]);
        const float M2 = fmaxf(d6[k + 1] - b[2], u6[k + 1] - b[6]);
        const float M3 = fmaxf(d6[k]     - b[3], u6[k + 2] - b[7]);

        const float m01 = b0 ? M1 : M0;
        const float m23 = b0 ? M3 : M2;
        const float Mj  = b1 ? m23 : m01;

        r[k] = (m[k] > Mj) ? m[k] : 0.0f;   // min(pos,neg)>0 <=> m>M[c&3]
    }
    v4f res; res.x = r[0]; res.y = r[1]; res.z = r[2]; res.w = r[3];
    return res;
}

__global__ __launch_bounds__(256) void nms_kernel(
    const float* __restrict__ mag,
    const float* __restrict__ orient,
    const float* __restrict__ bias,
    float* __restrict__ out)
{
    // XCD band swizzle: hardware maps blockIdx %8 -> XCD, so xcd = bid&7 and
    // each XCD owns a contiguous 512-row band (vertical halo re-reads stay
    // in the local L2). strip = 4 rows; 4 blocks cover a 4096-px row.
    const int bid   = blockIdx.x;
    const int xcd   = bid & 7;
    const int j     = bid >> 3;          // [0,512)
    const int sband = j >> 2;            // [0,128)
    const int bq    = j & 3;
    const int strip = xcd * 128 + sband; // [0,1024)

    const int x0 = (bq * 256 + threadIdx.x) << 2;   // [0,4096)
    const int y0 = strip << 2;                      // [0,4096), step 4

    const int   xL = (x0 > 0) ? x0 - 1 : 0;         // clamped halo columns
    const int   xR = (x0 + 4 < W) ? x0 + 4 : W - 1;
    const float lm = (x0 > 0) ? 1.f : 0.f;
    const float rm = (x0 + 4 < W) ? 1.f : 0.f;
    const float um = (y0 > 0) ? 1.f : 0.f;          // block-uniform
    const float dm = (y0 + 4 < H) ? 1.f : 0.f;

    // clamped row offsets for rows y0-1 .. y0+4 (block-uniform -> SGPRs)
    int rowoff[6];
    #pragma unroll
    for (int i = 0; i < 6; ++i) {
        int r = y0 + i - 1;
        r = (r < 0) ? 0 : ((r > H - 1) ? H - 1 : r);
        rowoff[i] = r << 12;
    }

    // ---- one clause: 6 dwordx4 mag + 12 dword halo + 4 dwordx4 orient ----
    v4f  A[6];
    float Lh[6], Rh[6];
    #pragma unroll
    for (int i = 0; i < 6; ++i) {
        A[i]  = *reinterpret_cast<const v4f*>(mag + rowoff[i] + x0);
        Lh[i] = mag[rowoff[i] + xL];
        Rh[i] = mag[rowoff[i] + xR];
    }
    v4f O[4];
    #pragma unroll
    for (int i = 0; i < 4; ++i)
        O[i] = *reinterpret_cast<const v4f*>(orient + rowoff[i + 1] + x0);

    float b[8];
    #pragma unroll
    for (int i = 0; i < 8; ++i) b[i] = bias[i];

    // ---- masked 6x6 window (0/1 multiplies; interior masks fold away) ----
    float Rm[6][6];
    #pragma unroll
    for (int i = 0; i < 6; ++i) {
        const float vm = (i == 0) ? um : ((i == 5) ? dm : 1.f);
        Rm[i][0] = Lh[i] * (lm * vm);
        Rm[i][1] = A[i].x * vm;
        Rm[i][2] = A[i].y * vm;
        Rm[i][3] = A[i].z * vm;
        Rm[i][4] = A[i].w * vm;
        Rm[i][5] = Rh[i] * (rm * vm);
    }

    // ---- 4 output rows; center magnitudes unmasked (rows y0..y0+3 valid) --
    #pragma unroll
    for (int jr = 0; jr < 4; ++jr) {
        const v4f res = nms_quad(Rm[jr], Rm[jr + 1], Rm[jr + 2],
                                 A[jr + 1], O[jr], b);
        __builtin_nontemporal_store(
            res, reinterpret_cast<v4f*>(out + rowoff[jr + 1] + x0));
    }
}

extern "C" void kernel_launch(void* const* d_in, const int* in_sizes, int n_in,
                              void* d_out, int out_size, void* d_ws, size_t ws_size,
                              hipStream_t stream) {
    const float* mag    = (const float*)d_in[0];   // [1,1,H,W]
    const float* orient = (const float*)d_in[1];   // [1,1,H,W]
    // d_in[2] = weight [8,1,3,3] -- fixed directional filters, hardcoded
    const float* bias   = (const float*)d_in[3];   // [8]
    float* out = (float*)d_out;                    // [1,1,H,W]

    const int total = (H / 4) * (W / 4);           // one thread per 4x4 px
    dim3 block(256);
    dim3 grid(total / 256);                        // 4096 blocks
    hipLaunchKernelGGL(nms_kernel, grid, block, 0, stream,
                       mag, orient, bias, out);
}